// Round 5
// baseline (3118.099 us; speedup 1.0000x reference)
//
#include <hip/hip_runtime.h>

typedef __bf16 bf16x8 __attribute__((ext_vector_type(8)));
typedef float f32x4 __attribute__((ext_vector_type(4)));
typedef unsigned int uint32;
typedef unsigned short u16;

#define T_STEPS 1024

// ---------------- LDS layout (byte offsets), 16B aligned ----------------
#define H0_OFF   0              // 2 ping-pong [16 rows][272B] (128 bf16 + 16B pad)
#define H1_OFF   8704
#define M1_OFF   17408          // [16][272B]
#define UCH_OFF  21760          // [32 s][16 r][48B] stride 784 -> 4-way not 32-way conflicts
#define YCH_OFF  46848
#define WL_OFF   71936          // 73 tiles x 1024B: [0..23]=Wih0, [24..28]=dC, [29..68]=mW1, [69..72]=mE
#define LDS_BYTES 146688
#define CH_STR   784

// ---------------- global frag buffer tiles (1 tile = 512 bf16 = 1KB) ----
#define TG0 0     // Wih0 [384,32]   KT=1 NT=24
#define TG1 24    // Whh0 [384,128]  KT=4 NT=24
#define TG2 120   // Wih1 [384,128]
#define TG3 216   // Whh1 [384,128]
#define TG4 312   // dC   [16,160]   KT=5 NT=1
#define TG5 317   // mW1  [128,160]  KT=5 NT=8
#define TG6 357   // mE   [16,128]   KT=4 NT=1
#define NT_TOT 361
#define SC_DC  369664
#define SC_ME  378880
#define SC_DBC 387072
#define SC_MBE 387136

static __device__ __forceinline__ u16 f2bf(float f) {
    uint32 u = __builtin_bit_cast(uint32, f);
    return (u16)((u + 0x7FFFu + ((u >> 16) & 1u)) >> 16);
}
static __device__ __forceinline__ float bf2f(u16 h) {
    uint32 u = ((uint32)h) << 16;
    return __builtin_bit_cast(float, u);
}
static __device__ __forceinline__ uint32 cvtpk(float a, float b) {
    uint32 r;
    asm("v_cvt_pk_bf16_f32 %0, %1, %2" : "=v"(r) : "v"(a), "v"(b));
    return r;
}
static __device__ __forceinline__ float sigm(float x) {
    return __builtin_amdgcn_rcpf(1.f + __builtin_amdgcn_exp2f(x * -1.4426950408889634f));
}
static __device__ __forceinline__ float tanh_fast(float x) {
    float xm = fmaxf(x, -30.f);
    float e = __builtin_amdgcn_exp2f(xm * -2.8853900817779268f);
    return fmaf(2.f, __builtin_amdgcn_rcpf(e + 1.f), -1.f);
}
static __device__ __forceinline__ f32x4 mfma16(bf16x8 a, bf16x8 b, f32x4 c) {
    return __builtin_amdgcn_mfma_f32_16x16x32_bf16(a, b, c, 0, 0, 0);
}
static __device__ __forceinline__ bf16x8 ldsAF(const char* p) {
    return __builtin_bit_cast(bf16x8, *(const uint4*)p);
}

// ---------------- prep1: combined matrices + biases (fp32), zero d_out ----------------
__global__ void prep1(const float* __restrict__ dW1, const float* __restrict__ db1,
                      const float* __restrict__ dW2, const float* __restrict__ db2,
                      const float* __restrict__ mW2, const float* __restrict__ mb2,
                      const float* __restrict__ mW3, const float* __restrict__ mb3,
                      char* __restrict__ ws, float* __restrict__ out) {
    int id = blockIdx.x * 256 + threadIdx.x;
    if (id == 0) *out = 0.f;
    if (id < 2304) {                       // dC[n][k] = sum_h dW2[n][h]*dW1[h][k]
        int n = id / 144, k = id % 144;
        float s = 0.f;
        for (int h = 0; h < 128; ++h) s += dW2[n * 128 + h] * dW1[h * 144 + k];
        ((float*)(ws + SC_DC))[id] = s;
    } else if (id < 4352) {                // mE[n][k] = sum_h mW3[n][h]*mW2[h][k]
        int e = id - 2304, n = e / 128, k = e % 128;
        float s = 0.f;
        for (int h = 0; h < 128; ++h) s += mW3[n * 128 + h] * mW2[h * 128 + k];
        ((float*)(ws + SC_ME))[e] = s;
    } else if (id < 4368) {                // dbC = dW2@db1 + db2
        int n = id - 4352;
        float s = db2[n];
        for (int h = 0; h < 128; ++h) s += dW2[n * 128 + h] * db1[h];
        ((float*)(ws + SC_DBC))[n] = s;
    } else if (id < 4384) {                // mbE = mW3@mb2 + mb3
        int n = id - 4368;
        float s = mb3[n];
        for (int h = 0; h < 128; ++h) s += mW3[n * 128 + h] * mb2[h];
        ((float*)(ws + SC_MBE))[n] = s;
    }
}

// ---------------- prep2: pack weights into MFMA B-fragment order (bf16) ----------------
__global__ void prep2(const float* __restrict__ W0, const float* __restrict__ W1,
                      const float* __restrict__ W2, const float* __restrict__ W3,
                      const float* __restrict__ W5, char* __restrict__ ws) {
    const int tt = blockIdx.x;     // 0..360
    const int lane = threadIdx.x;  // 0..63
    const int cum[8] = {TG0, TG1, TG2, TG3, TG4, TG5, TG6, NT_TOT};
    const int Kreal[7] = {32, 128, 128, 128, 144, 144, 128};
    const int KT[7] = {1, 4, 4, 4, 5, 5, 4};
    const float* Ws[7] = {W0, W1, W2, W3, (const float*)(ws + SC_DC), W5, (const float*)(ws + SC_ME)};
    int g = 0;
    while (tt >= cum[g + 1]) ++g;
    const int tl = tt - cum[g];
    const int kt = tl % KT[g];
    const int n = (tl / KT[g]) * 16 + (lane & 15);
    const float* W = Ws[g];
    u16* o = (u16*)ws + tt * 512 + lane * 8;
#pragma unroll
    for (int j = 0; j < 8; ++j) {
        int k = kt * 32 + (lane >> 4) * 8 + j;
        o[j] = (k < Kreal[g]) ? f2bf(W[n * Kreal[g] + k]) : (u16)0;
    }
}

// ---------------- main: 16 WG x 256 thr (4 waves, 1 wave/SIMD, 512-reg budget) ----------
__global__ __launch_bounds__(256, 1) void rnn_main(
    const float* __restrict__ u, const float* __restrict__ yg, const float* __restrict__ h0g,
    const char* __restrict__ ws, const float* __restrict__ mb1g,
    const float* __restrict__ dbCg, const float* __restrict__ mbEg,
    float* __restrict__ out) {
    __shared__ __align__(16) char smem[LDS_BYTES];
    const int tid = threadIdx.x;
    const int lane = tid & 63;
    const int w = tid >> 6;       // wave 0..3: owns cols [w*32, w*32+32)
    const int lr = lane & 15;
    const int lg = lane >> 4;
    const int r0 = blockIdx.x * 16;
    const uint4* F4 = (const uint4*)ws;
    const f32x4 zero = {0.f, 0.f, 0.f, 0.f};

    // ---- init: load h0 -> LDS bf16 (buffer 0), copy LDS-resident weights ----
    for (int i = tid; i < 1024; i += 256) {  // 2 layers x 16 rows x 32 float4
        int lay = i >> 9, rem = i & 511, rr = rem >> 5, k4 = rem & 31;
        float4 v = *(const float4*)(h0g + (lay * 256 + r0 + rr) * 128 + k4 * 4);
        uint2 pk;
        pk.x = (uint32)f2bf(v.x) | ((uint32)f2bf(v.y) << 16);
        pk.y = (uint32)f2bf(v.z) | ((uint32)f2bf(v.w) << 16);
        *(uint2*)(smem + H0_OFF + lay * 8704 + rr * 272 + k4 * 8) = pk;
    }
    for (int i = tid; i < 73 * 64; i += 256) {  // Wih0,dC,mW1,mE -> WL
        int li = i >> 6, ln2 = i & 63;
        int gt2 = (li < 24) ? li : (li < 29) ? TG4 + (li - 24) : (li < 69) ? TG5 + (li - 29) : TG6 + (li - 69);
        *((uint4*)(smem + WL_OFF) + i) = F4[gt2 * 64 + ln2];
    }
    __syncthreads();

    // ---- per-wave register weights (Whh0/Wih1/Whh1 for 2 col-tiles), staged THROUGH LDS
    //      so the compiler cannot rematerialize the loads inside the t-loop ----
    bf16x8 wW[3][3][2][4];  // [mat][gate][coltile j][kt]; mat 0=Whh0 1=Wih1 2=Whh1
    for (int p = 0; p < 6; ++p) {
        for (int i = tid; i < 3072; i += 256)
            *((uint4*)(smem + UCH_OFF) + i) = F4[(TG1 + p * 48) * 64 + i];
        __syncthreads();
#pragma unroll
        for (int mat = 0; mat < 3; ++mat)
#pragma unroll
            for (int gg = 0; gg < 3; ++gg)
#pragma unroll
                for (int j = 0; j < 2; ++j) {
                    int rel0 = mat * 96 + gg * 32 + (2 * w + j) * 4;
                    if (rel0 >= p * 48 && rel0 < p * 48 + 48) {
#pragma unroll
                        for (int kt = 0; kt < 4; ++kt)
                            wW[mat][gg][j][kt] =
                                ldsAF(smem + UCH_OFF + (rel0 - p * 48 + kt) * 1024 + lane * 16);
                    }
                }
        __syncthreads();
    }

    // ---- per-lane constants & register-resident hold state ----
    float mb1_c[2] = {mb1g[w * 32 + lr], mb1g[w * 32 + 16 + lr]};
    const float mbE_l = mbEg[lr];
    float dbc4[4];
#pragma unroll
    for (int i = 0; i < 4; ++i) dbc4[i] = dbCg[lg * 4 + i];
    float hp0[2][4], hp1[2][4];
#pragma unroll
    for (int j = 0; j < 2; ++j)
#pragma unroll
        for (int i = 0; i < 4; ++i) {
            hp0[j][i] = h0g[(r0 + lg * 4 + i) * 128 + w * 32 + j * 16 + lr];
            hp1[j][i] = h0g[(256 + r0 + lg * 4 + i) * 128 + w * 32 + j * 16 + lr];
        }
    float loss = 0.f;
    const int bp0 = (lr + (lg & 1) * 32) * 4;  // bpermute byte-addr of x source lane

    // initial ah prefetch (h0c of t=0 = buffer 0)
    bf16x8 pf_ah[4];
#pragma unroll
    for (int kt = 0; kt < 4; ++kt) pf_ah[kt] = ldsAF(smem + H0_OFF + lr * 272 + kt * 64 + lg * 16);

#pragma unroll 2
    for (int t = 0; t < T_STEPS; ++t) {
        const char* h0c = smem + H0_OFF + (t & 1) * 4352;
        char* h0n = smem + H0_OFF + ((t & 1) ^ 1) * 4352;
        const char* h1c = smem + H1_OFF + (t & 1) * 4352;
        char* h1n = smem + H1_OFF + ((t & 1) ^ 1) * 4352;
        const int s = t & 31, sp = (t - 1) & 31;
        const char* h1r = h1c + lr * 272;

        // ---- issue x-input reads (old chunk slot sp + h1c + dC) ----
        bf16x8 ad0 = ldsAF((lg < 2) ? (smem + UCH_OFF + sp * CH_STR + lr * 48 + lg * 16)
                                    : (h1r + (lg - 2) * 16));
        bf16x8 ad1 = ldsAF(h1r + 32 + lg * 16);
        bf16x8 ad2 = ldsAF(h1r + 96 + lg * 16);
        bf16x8 ad3 = ldsAF(h1r + 160 + lg * 16);
        bf16x8 ad4 = ldsAF(h1r + 224 + (lg & 1) * 16);  // lg>=2 lanes: K-pad, B is zero there
        bf16x8 wd0 = ldsAF(smem + WL_OFF + 24 * 1024 + lane * 16);
        bf16x8 wd1 = ldsAF(smem + WL_OFF + 25 * 1024 + lane * 16);
        bf16x8 wd2 = ldsAF(smem + WL_OFF + 26 * 1024 + lane * 16);
        bf16x8 wd3 = ldsAF(smem + WL_OFF + 27 * 1024 + lane * 16);
        bf16x8 wd4 = ldsAF(smem + WL_OFF + 28 * 1024 + lane * 16);

        // ---- GRU0 h-part first: 24 MFMA on prefetched ah (hides x-read latency) ----
        f32x4 hR[2], hZ[2], hN[2], nI[2];
#pragma unroll
        for (int j = 0; j < 2; ++j) { hR[j] = zero; hZ[j] = zero; hN[j] = zero; }
#pragma unroll
        for (int kt = 0; kt < 4; ++kt)
#pragma unroll
            for (int j = 0; j < 2; ++j) {
                hR[j] = mfma16(pf_ah[kt], wW[0][0][j][kt], hR[j]);
                hZ[j] = mfma16(pf_ah[kt], wW[0][1][j][kt], hZ[j]);
                hN[j] = mfma16(pf_ah[kt], wW[0][2][j][kt], hN[j]);
            }

        // ---- x(t-1) = [u(t-1)|h1(t-1)] @ dC^T + dbC (redundant per wave, in-register) ----
        f32x4 xa = mfma16(wd0, ad0, zero);
        xa = mfma16(wd1, ad1, xa);
        xa = mfma16(wd2, ad2, xa);
        f32x4 xb = mfma16(wd3, ad3, zero);
        xb = mfma16(wd4, ad4, xb);
        uint32 pk0 = cvtpk(xa[0] + xb[0] + dbc4[0], xa[1] + xb[1] + dbc4[1]);
        uint32 pk1 = cvtpk(xa[2] + xb[2] + dbc4[2], xa[3] + xb[3] + dbc4[3]);
        if (t == 0) { pk0 = 0u; pk1 = 0u; }
        uint32 d0 = (uint32)__builtin_amdgcn_ds_bpermute(bp0, (int)pk0);
        uint32 d1 = (uint32)__builtin_amdgcn_ds_bpermute(bp0, (int)pk1);
        uint32 d2 = (uint32)__builtin_amdgcn_ds_bpermute(bp0 + 64, (int)pk0);
        uint32 d3 = (uint32)__builtin_amdgcn_ds_bpermute(bp0 + 64, (int)pk1);
        bf16x8 xfrag = __builtin_bit_cast(bf16x8, (uint4){d0, d1, d2, d3});

        // ---- chunk refill every 32 steps ----
        if ((t & 31) == 0) {
            __syncthreads();
            for (int q = 0; q < 32; ++q) {
                int pair = w * 64 + q * 2 + (lane >> 5);
                int rr2 = pair >> 4, ch = pair & 15, ss = lane & 31;
                float v = u[(r0 + rr2) * 16384 + ch * 1024 + t + ss];
                *(u16*)(smem + UCH_OFF + ss * CH_STR + rr2 * 48 + ch * 2) = f2bf(v);
                int gt = t - 1 + ss;
                if (gt >= 0) {
                    float vy = yg[(r0 + rr2) * 16384 + ch * 1024 + gt];
                    *(u16*)(smem + YCH_OFF + ss * CH_STR + rr2 * 48 + ch * 2) = f2bf(vy);
                }
            }
            __syncthreads();
        }

        // ---- GRU0 input-part + m1(t-1) ----
        bf16x8 ufrag = ldsAF(smem + UCH_OFF + s * CH_STR + lr * 48 + (lg & 1) * 16);
        bf16x8 a_inp = (lg < 2) ? ufrag : xfrag;
#pragma unroll
        for (int j = 0; j < 2; ++j) {
            bf16x8 b0r = ldsAF(smem + WL_OFF + (0 * 8 + 2 * w + j) * 1024 + lane * 16);
            bf16x8 b0z = ldsAF(smem + WL_OFF + (1 * 8 + 2 * w + j) * 1024 + lane * 16);
            bf16x8 b0n = ldsAF(smem + WL_OFF + (2 * 8 + 2 * w + j) * 1024 + lane * 16);
            hR[j] = mfma16(a_inp, b0r, hR[j]);
            hZ[j] = mfma16(a_inp, b0z, hZ[j]);
            nI[j] = mfma16(a_inp, b0n, zero);
        }
        const char* h0r = h0c + lr * 272;
        bf16x8 am0 = (lg < 2) ? xfrag : ldsAF(h0r + (lg - 2) * 16);
        bf16x8 am1 = ldsAF(h0r + 32 + lg * 16);
        bf16x8 am2 = ldsAF(h0r + 96 + lg * 16);
        bf16x8 am3 = ldsAF(h0r + 160 + lg * 16);
        bf16x8 am4 = ldsAF(h0r + 224 + (lg & 1) * 16);  // K-pad cols: B zero
        f32x4 m[2];
#pragma unroll
        for (int j = 0; j < 2; ++j) {
            const int mb = 29 + (2 * w + j) * 5;
            m[j] = mfma16(am1, ldsAF(smem + WL_OFF + (mb + 1) * 1024 + lane * 16), zero);
            m[j] = mfma16(am2, ldsAF(smem + WL_OFF + (mb + 2) * 1024 + lane * 16), m[j]);
            m[j] = mfma16(am0, ldsAF(smem + WL_OFF + (mb + 0) * 1024 + lane * 16), m[j]);
            m[j] = mfma16(am3, ldsAF(smem + WL_OFF + (mb + 3) * 1024 + lane * 16), m[j]);
            m[j] = mfma16(am4, ldsAF(smem + WL_OFF + (mb + 4) * 1024 + lane * 16), m[j]);
        }
#pragma unroll
        for (int j = 0; j < 2; ++j) {
            const int c2 = (w * 32 + j * 16 + lr) * 2;
#pragma unroll
            for (int i = 0; i < 4; ++i) {
                float rr = sigm(hR[j][i]);
                float zz = sigm(hZ[j][i]);
                float nn = tanh_fast(fmaf(rr, hN[j][i], nI[j][i]));
                float hnew = fmaf(zz, hp0[j][i] - nn, nn);
                hp0[j][i] = hnew;
                *(u16*)(h0n + (lg * 4 + i) * 272 + c2) = (u16)cvtpk(hnew, hnew);
                float mv = fmaxf(m[j][i] + mb1_c[j], 0.f);
                *(u16*)(smem + M1_OFF + (lg * 4 + i) * 272 + c2) = (u16)cvtpk(mv, mv);
            }
        }
        // prefetch h1c fragments for phase 2 (h1c is stable this step)
        bf16x8 pf_av[4];
#pragma unroll
        for (int kt = 0; kt < 4; ++kt) pf_av[kt] = ldsAF(h1r + kt * 64 + lg * 16);
        __syncthreads();

        // ================= PHASE 2: GRU1(t) + loss(t-1) =================
        const char* h0nr = h0n + lr * 272;
        bf16x8 ag[4];
#pragma unroll
        for (int kt = 0; kt < 4; ++kt) ag[kt] = ldsAF(h0nr + kt * 64 + lg * 16);
        bf16x8 q0, q1, q2, q3, we0, we1, we2, we3;
        if (w == 3) {
            const char* m1r = smem + M1_OFF + lr * 272;
            q0 = ldsAF(m1r + lg * 16);
            q1 = ldsAF(m1r + 64 + lg * 16);
            q2 = ldsAF(m1r + 128 + lg * 16);
            q3 = ldsAF(m1r + 192 + lg * 16);
            we0 = ldsAF(smem + WL_OFF + 69 * 1024 + lane * 16);
            we1 = ldsAF(smem + WL_OFF + 70 * 1024 + lane * 16);
            we2 = ldsAF(smem + WL_OFF + 71 * 1024 + lane * 16);
            we3 = ldsAF(smem + WL_OFF + 72 * 1024 + lane * 16);
        }
        f32x4 R[2], Z[2], Nh[2], Ni[2];
#pragma unroll
        for (int j = 0; j < 2; ++j) { R[j] = zero; Z[j] = zero; Nh[j] = zero; Ni[j] = zero; }
        // av-based first (prefetched), hides post-barrier ag latency
#pragma unroll
        for (int kt = 0; kt < 4; ++kt)
#pragma unroll
            for (int j = 0; j < 2; ++j) {
                R[j] = mfma16(pf_av[kt], wW[2][0][j][kt], R[j]);
                Z[j] = mfma16(pf_av[kt], wW[2][1][j][kt], Z[j]);
                Nh[j] = mfma16(pf_av[kt], wW[2][2][j][kt], Nh[j]);
            }
#pragma unroll
        for (int kt = 0; kt < 4; ++kt)
#pragma unroll
            for (int j = 0; j < 2; ++j) {
                R[j] = mfma16(ag[kt], wW[1][0][j][kt], R[j]);
                Z[j] = mfma16(ag[kt], wW[1][1][j][kt], Z[j]);
                Ni[j] = mfma16(ag[kt], wW[1][2][j][kt], Ni[j]);
            }
        if (w == 3) {  // y_hat(t-1) = m1(t-1) @ mE^T + mbE ; loss
            f32x4 lA = mfma16(q0, we0, zero);
            lA = mfma16(q1, we1, lA);
            f32x4 lB = mfma16(q2, we2, zero);
            lB = mfma16(q3, we3, lB);
            const float gd = (t > 0) ? 1.f : 0.f;
#pragma unroll
            for (int i = 0; i < 4; ++i) {
                float yh = lA[i] + lB[i] + mbE_l;
                float yv = bf2f(*(const u16*)(smem + YCH_OFF + s * CH_STR + (lg * 4 + i) * 48 + lr * 2));
                float d = yh - yv;
                loss = fmaf(gd * d, d, loss);
            }
        }
#pragma unroll
        for (int j = 0; j < 2; ++j) {
            const int c2 = (w * 32 + j * 16 + lr) * 2;
#pragma unroll
            for (int i = 0; i < 4; ++i) {
                float rr = sigm(R[j][i]);
                float zz = sigm(Z[j][i]);
                float nn = tanh_fast(fmaf(rr, Nh[j][i], Ni[j][i]));
                float hnew = fmaf(zz, hp1[j][i] - nn, nn);
                hp1[j][i] = hnew;
                *(u16*)(h1n + (lg * 4 + i) * 272 + c2) = (u16)cvtpk(hnew, hnew);
            }
        }
        // ag(t) fragments ARE next step's ah fragments (same LDS rows) — free prefetch
#pragma unroll
        for (int kt = 0; kt < 4; ++kt) pf_ah[kt] = ag[kt];
        __syncthreads();
    }

    // ================= tail: m1(1023) + loss(1023) =================
    {
        const char* h0c = smem + H0_OFF;   // buffer 0 = h0n(1023)
        const char* h1c = smem + H1_OFF;   // buffer 0 = h1n(1023)
        const char* h1r = h1c + lr * 272;
        const char* h0r = h0c + lr * 272;
        bf16x8 ad0 = ldsAF((lg < 2) ? (smem + UCH_OFF + 31 * CH_STR + lr * 48 + lg * 16)
                                    : (h1r + (lg - 2) * 16));
        bf16x8 ad1 = ldsAF(h1r + 32 + lg * 16);
        bf16x8 ad2 = ldsAF(h1r + 96 + lg * 16);
        bf16x8 ad3 = ldsAF(h1r + 160 + lg * 16);
        bf16x8 ad4 = ldsAF(h1r + 224 + (lg & 1) * 16);
        f32x4 xa = mfma16(ldsAF(smem + WL_OFF + 24 * 1024 + lane * 16), ad0, zero);
        xa = mfma16(ldsAF(smem + WL_OFF + 25 * 1024 + lane * 16), ad1, xa);
        xa = mfma16(ldsAF(smem + WL_OFF + 26 * 1024 + lane * 16), ad2, xa);
        f32x4 xb = mfma16(ldsAF(smem + WL_OFF + 27 * 1024 + lane * 16), ad3, zero);
        xb = mfma16(ldsAF(smem + WL_OFF + 28 * 1024 + lane * 16), ad4, xb);
        uint32 pk0 = cvtpk(xa[0] + xb[0] + dbc4[0], xa[1] + xb[1] + dbc4[1]);
        uint32 pk1 = cvtpk(xa[2] + xb[2] + dbc4[2], xa[3] + xb[3] + dbc4[3]);
        uint32 d0 = (uint32)__builtin_amdgcn_ds_bpermute(bp0, (int)pk0);
        uint32 d1 = (uint32)__builtin_amdgcn_ds_bpermute(bp0, (int)pk1);
        uint32 d2 = (uint32)__builtin_amdgcn_ds_bpermute(bp0 + 64, (int)pk0);
        uint32 d3 = (uint32)__builtin_amdgcn_ds_bpermute(bp0 + 64, (int)pk1);
        bf16x8 xfrag = __builtin_bit_cast(bf16x8, (uint4){d0, d1, d2, d3});
        bf16x8 am0 = (lg < 2) ? xfrag : ldsAF(h0r + (lg - 2) * 16);
        bf16x8 am1 = ldsAF(h0r + 32 + lg * 16);
        bf16x8 am2 = ldsAF(h0r + 96 + lg * 16);
        bf16x8 am3 = ldsAF(h0r + 160 + lg * 16);
        bf16x8 am4 = ldsAF(h0r + 224 + (lg & 1) * 16);
#pragma unroll
        for (int j = 0; j < 2; ++j) {
            const int mb = 29 + (2 * w + j) * 5;
            f32x4 m = mfma16(am0, ldsAF(smem + WL_OFF + (mb + 0) * 1024 + lane * 16), zero);
            m = mfma16(am1, ldsAF(smem + WL_OFF + (mb + 1) * 1024 + lane * 16), m);
            m = mfma16(am2, ldsAF(smem + WL_OFF + (mb + 2) * 1024 + lane * 16), m);
            m = mfma16(am3, ldsAF(smem + WL_OFF + (mb + 3) * 1024 + lane * 16), m);
            m = mfma16(am4, ldsAF(smem + WL_OFF + (mb + 4) * 1024 + lane * 16), m);
            const int c2 = (w * 32 + j * 16 + lr) * 2;
#pragma unroll
            for (int i = 0; i < 4; ++i) {
                float mv = fmaxf(m[i] + mb1_c[j], 0.f);
                *(u16*)(smem + M1_OFF + (lg * 4 + i) * 272 + c2) = (u16)cvtpk(mv, mv);
            }
        }
        __syncthreads();
        if (w == 3) {
            const char* m1r = smem + M1_OFF + lr * 272;
            bf16x8 q0 = ldsAF(m1r + lg * 16);
            bf16x8 q1 = ldsAF(m1r + 64 + lg * 16);
            bf16x8 q2 = ldsAF(m1r + 128 + lg * 16);
            bf16x8 q3 = ldsAF(m1r + 192 + lg * 16);
            f32x4 lA = mfma16(q0, ldsAF(smem + WL_OFF + 69 * 1024 + lane * 16), zero);
            lA = mfma16(q1, ldsAF(smem + WL_OFF + 70 * 1024 + lane * 16), lA);
            f32x4 lB = mfma16(q2, ldsAF(smem + WL_OFF + 71 * 1024 + lane * 16), zero);
            lB = mfma16(q3, ldsAF(smem + WL_OFF + 72 * 1024 + lane * 16), lB);
#pragma unroll
            for (int i = 0; i < 4; ++i) {
                float yh = lA[i] + lB[i] + mbE_l;
                float yv = yg[(r0 + lg * 4 + i) * 16384 + lr * 1024 + 1023];
                float d = yh - yv;
                loss = fmaf(d, d, loss);
            }
        }
    }

    if (w == 3) {
#pragma unroll
        for (int off = 32; off > 0; off >>= 1) loss += __shfl_down(loss, off, 64);
        if (lane == 0) atomicAdd(out, loss);
    }
}

extern "C" void kernel_launch(void* const* d_in, const int* in_sizes, int n_in,
                              void* d_out, int out_size, void* d_ws, size_t ws_size,
                              hipStream_t stream) {
    const float* u    = (const float*)d_in[0];
    const float* y    = (const float*)d_in[1];
    const float* h0   = (const float*)d_in[2];
    const float* Wih0 = (const float*)d_in[3];
    const float* Whh0 = (const float*)d_in[4];
    const float* Wih1 = (const float*)d_in[5];
    const float* Whh1 = (const float*)d_in[6];
    const float* dW1  = (const float*)d_in[7];
    const float* db1  = (const float*)d_in[8];
    const float* dW2  = (const float*)d_in[9];
    const float* db2  = (const float*)d_in[10];
    const float* mW1  = (const float*)d_in[11];
    const float* mb1  = (const float*)d_in[12];
    const float* mW2  = (const float*)d_in[13];
    const float* mb2  = (const float*)d_in[14];
    const float* mW3  = (const float*)d_in[15];
    const float* mb3  = (const float*)d_in[16];
    float* out = (float*)d_out;
    char* ws = (char*)d_ws;

    prep1<<<dim3(18), dim3(256), 0, stream>>>(dW1, db1, dW2, db2, mW2, mb2, mW3, mb3, ws, out);
    prep2<<<dim3(NT_TOT), dim3(64), 0, stream>>>(Wih0, Whh0, Wih1, Whh1, mW1, ws);
    rnn_main<<<dim3(16), dim3(256), 0, stream>>>(u, y, h0, ws, mb1,
                                                 (const float*)(ws + SC_DBC),
                                                 (const float*)(ws + SC_MBE), out);
}